// Round 4
// baseline (1067.760 us; speedup 1.0000x reference)
//
#include <hip/hip_runtime.h>

#define NN 100000   // nodes
#define NE 1000000  // edges
#define FD 64       // feature dim
#define NB 8        // nodes per wave iteration in k_l1 (NN % NB == 0)
#define NBLK 98     // scan blocks: ceil(NN/1024)

// ws layout (4-byte units):
//   deg      : [0, NN)              int
//   rowstart : [NN, 2NN)            int   (exclusive scan of deg)
//   partial  : [2NN, 2NN+128)       int   (scan block sums)
//   rank     : [2NN+128, +NE)       int   (edge rank within its dst row)
//   csr      : [2NN+128+NE, +NE)    int   (src ids grouped by dst)
//   pq       : [2NN+128+2NE, +4NN)  float (p0,p1,q0,q1 per node)
// total ~ 10.4 MB

#define OFF_DEG 0
#define OFF_ROW (NN)
#define OFF_PAR (2 * NN)
#define OFF_RANK (2 * NN + 128)
#define OFF_CSR (2 * NN + 128 + NE)
#define OFF_PQ  (2 * NN + 128 + 2 * NE)

// ---------------------------------------------------------------------------
// K1: in-degree counts + per-edge rank within its dst row.
__global__ void k_prep(const int* __restrict__ ei, int* __restrict__ deg,
                       int* __restrict__ rank) {
    int stride = gridDim.x * blockDim.x;
    for (int e = blockIdx.x * blockDim.x + threadIdx.x; e < NE; e += stride) {
        int d = ei[NE + e];
        rank[e] = atomicAdd(&deg[d], 1);
    }
}

// ---------------------------------------------------------------------------
// K2a: per-block (1024-elem) sums of deg -> partial[b]
__global__ __launch_bounds__(256) void k_scanA(const int* __restrict__ deg,
                                               int* __restrict__ partial) {
    __shared__ int lds[256];
    int t = threadIdx.x;
    int base = blockIdx.x * 1024 + t * 4;
    int s_t = 0;
    if (base < NN) {  // NN % 4 == 0
        int4 v = *(const int4*)(deg + base);
        s_t = v.x + v.y + v.z + v.w;
    }
    lds[t] = s_t;
    __syncthreads();
    for (int s = 128; s; s >>= 1) {
        if (t < s) lds[t] += lds[t + s];
        __syncthreads();
    }
    if (t == 0) partial[blockIdx.x] = lds[0];
}

// K2b: block offset + intra-block exclusive scan -> rowstart[i]
__global__ __launch_bounds__(256) void k_scanB(const int* __restrict__ deg,
                                               const int* __restrict__ partial,
                                               int* __restrict__ rowstart) {
    __shared__ int lds[256];
    int t = threadIdx.x, b = blockIdx.x;
    lds[t] = (t < b && t < NBLK) ? partial[t] : 0;
    __syncthreads();
    for (int s = 128; s; s >>= 1) {
        if (t < s) lds[t] += lds[t + s];
        __syncthreads();
    }
    int bo = lds[0];
    __syncthreads();

    int base = b * 1024 + t * 4;
    int4 v = make_int4(0, 0, 0, 0);
    if (base < NN) v = *(const int4*)(deg + base);
    int s_t = v.x + v.y + v.z + v.w;

    lds[t] = s_t;
    __syncthreads();
    for (int off = 1; off < 256; off <<= 1) {
        int v2 = lds[t];
        if (t >= off) v2 += lds[t - off];
        __syncthreads();
        lds[t] = v2;
        __syncthreads();
    }
    int excl = lds[t] - s_t;
    if (base < NN) {
        int r = bo + excl;
        int4 out;
        out.x = r;
        out.y = r + v.x;
        out.z = r + v.x + v.y;
        out.w = r + v.x + v.y + v.z;
        *(int4*)(rowstart + base) = out;
    }
}

// ---------------------------------------------------------------------------
// K3: pure scatter (no atomics): csr[rowstart[d]+rank[e]] = s; also emit
//     edge_index as float to the output tail.
__global__ void k_build(const int* __restrict__ ei, const int* __restrict__ rowstart,
                        const int* __restrict__ rank, int* __restrict__ csr,
                        float* __restrict__ edge_out) {
    int stride = gridDim.x * blockDim.x;
    for (int e = blockIdx.x * blockDim.x + threadIdx.x; e < NE; e += stride) {
        int s = ei[e];
        int d = ei[NE + e];
        edge_out[e] = (float)s;
        edge_out[NE + e] = (float)d;
        csr[rowstart[d] + rank[e]] = s;
    }
}

// ---------------------------------------------------------------------------
// K4: fused layer-1, NB nodes per wave iteration.
//  phase A (per node): lane=feature mean-gather (4-way unrolled, readlane for
//    scalar base addresses) -> LDS srow/xrow.
//  phase B: one sweep over W1l/W1r; each float4 of W feeds NB nodes' FMAs
//    (8x fewer weight loads per node).
//  phase C (per node): h=relu(...), wave-reduce to pq[n] (float4).
__global__ __launch_bounds__(256) void k_l1(
    const int* __restrict__ csr, const int* __restrict__ rowstart,
    const int* __restrict__ deg, const float* __restrict__ x,
    const float* __restrict__ W1l, const float* __restrict__ b1,
    const float* __restrict__ W1r,
    const float* __restrict__ W2l, const float* __restrict__ b2,
    const float* __restrict__ W2r,
    float* __restrict__ pq) {
    __shared__ float srow[4][NB][FD];
    __shared__ float xrow[4][NB][FD];
    __shared__ float sinv[4][NB];
    const int lane = threadIdx.x & 63;
    const int wid = threadIdx.x >> 6;
    const int gw = (blockIdx.x * blockDim.x + threadIdx.x) >> 6;
    const int nwav = (gridDim.x * blockDim.x) >> 6;

    const float b1k = b1[lane];
    const float w2l0 = W2l[lane], w2l1 = W2l[FD + lane];
    const float w2r0 = W2r[lane], w2r1 = W2r[FD + lane];
    const float b20 = b2[0], b21 = b2[1];

    for (int c = gw; c < NN / NB; c += nwav) {
        const int base = c * NB;
        // ---- phase A: gather NB rows (not unrolled: keep regs low) ----
#pragma unroll 1
        for (int nb = 0; nb < NB; ++nb) {
            const int n = base + nb;
            const int rs = rowstart[n];
            const int d = deg[n];
            const int dm = min(d, 64);
            int srcj = (lane < dm) ? csr[rs + lane] : 0;
            float acc0 = 0.f, acc1 = 0.f;
            int j = 0;
            for (; j + 4 <= dm; j += 4) {
                int s0 = __builtin_amdgcn_readlane(srcj, j);
                int s1 = __builtin_amdgcn_readlane(srcj, j + 1);
                int s2 = __builtin_amdgcn_readlane(srcj, j + 2);
                int s3 = __builtin_amdgcn_readlane(srcj, j + 3);
                float v0 = x[(size_t)s0 * FD + lane];
                float v1 = x[(size_t)s1 * FD + lane];
                float v2 = x[(size_t)s2 * FD + lane];
                float v3 = x[(size_t)s3 * FD + lane];
                acc0 += v0 + v2;
                acc1 += v1 + v3;
            }
            for (; j < dm; ++j) {
                int s0 = __builtin_amdgcn_readlane(srcj, j);
                acc0 += x[(size_t)s0 * FD + lane];
            }
            for (int e = rs + 64; e < rs + d; ++e)  // deg>64 tail (rare)
                acc1 += x[(size_t)csr[e] * FD + lane];
            float invc = 1.0f / (float)max(d, 1);
            srow[wid][nb][lane] = (acc0 + acc1) * invc;
            xrow[wid][nb][lane] = x[(size_t)n * FD + lane];
            if (lane == 0) sinv[wid][nb] = invc;
        }
        asm volatile("s_waitcnt lgkmcnt(0)" ::: "memory");

        // ---- phase B: weight sweep amortized over NB nodes ----
        float accA[NB], accR[NB];
#pragma unroll
        for (int nb = 0; nb < NB; ++nb) { accA[nb] = 0.f; accR[nb] = 0.f; }
#pragma unroll
        for (int j4 = 0; j4 < FD / 4; ++j4) {
            const float4 wlv = *(const float4*)(W1l + (size_t)lane * FD + 4 * j4);
            const float4 wrv = *(const float4*)(W1r + (size_t)lane * FD + 4 * j4);
#pragma unroll
            for (int nb = 0; nb < NB; ++nb) {
                const float4 s = *(const float4*)(&srow[wid][nb][4 * j4]);
                const float4 xx = *(const float4*)(&xrow[wid][nb][4 * j4]);
                accA[nb] += s.x * wlv.x + s.y * wlv.y + s.z * wlv.z + s.w * wlv.w;
                accR[nb] += xx.x * wrv.x + xx.y * wrv.y + xx.z * wrv.z + xx.w * wrv.w;
            }
        }

        // ---- phase C: relu + projections + wave reductions ----
#pragma unroll
        for (int nb = 0; nb < NB; ++nb) {
            float h = fmaxf(accA[nb] + accR[nb] + b1k, 0.f);
            // NOTE: srow already divided by cnt; accA needs no further scale.
            (void)sinv;
            float p0 = h * w2l0, p1 = h * w2l1;
            float q0 = h * w2r0, q1 = h * w2r1;
#pragma unroll
            for (int off = 32; off; off >>= 1) {
                p0 += __shfl_xor(p0, off);
                p1 += __shfl_xor(p1, off);
                q0 += __shfl_xor(q0, off);
                q1 += __shfl_xor(q1, off);
            }
            if (lane == 0)
                *(float4*)(pq + 4 * (size_t)(base + nb)) =
                    make_float4(p0, p1, q0 + b20, q1 + b21);
        }
    }
}

// ---------------------------------------------------------------------------
// K5: layer-2 mean aggregation of p (8B gathers, L2/L3-resident) + final add.
__global__ void k_l2(const int* __restrict__ csr, const int* __restrict__ rowstart,
                     const int* __restrict__ deg, const float* __restrict__ pq,
                     float* __restrict__ out) {
    int n = blockIdx.x * blockDim.x + threadIdx.x;
    if (n >= NN) return;
    int rs = rowstart[n];
    int d = deg[n];
    float a0 = 0.f, a1 = 0.f, c0 = 0.f, c1 = 0.f;
    int i = 0;
    for (; i + 2 <= d; i += 2) {
        int s0 = csr[rs + i];
        int s1 = csr[rs + i + 1];
        float2 v0 = *(const float2*)(pq + 4 * (size_t)s0);
        float2 v1 = *(const float2*)(pq + 4 * (size_t)s1);
        a0 += v0.x; a1 += v0.y;
        c0 += v1.x; c1 += v1.y;
    }
    if (i < d) {
        int s0 = csr[rs + i];
        float2 v0 = *(const float2*)(pq + 4 * (size_t)s0);
        a0 += v0.x; a1 += v0.y;
    }
    float inv = 1.0f / (float)max(d, 1);
    float2 q = *(const float2*)(pq + 4 * (size_t)n + 2);
    *(float2*)(out + 2 * (size_t)n) =
        make_float2((a0 + c0) * inv + q.x, (a1 + c1) * inv + q.y);
}

// ---------------------------------------------------------------------------
extern "C" void kernel_launch(void* const* d_in, const int* in_sizes, int n_in,
                              void* d_out, int out_size, void* d_ws, size_t ws_size,
                              hipStream_t stream) {
    const float* x   = (const float*)d_in[0];
    const int*   ei  = (const int*)d_in[1];
    const float* W1l = (const float*)d_in[2];
    const float* b1  = (const float*)d_in[3];
    const float* W1r = (const float*)d_in[4];
    const float* W2l = (const float*)d_in[5];
    const float* b2  = (const float*)d_in[6];
    const float* W2r = (const float*)d_in[7];

    float* out      = (float*)d_out;   // N*2 floats
    float* edge_out = out + 2 * NN;    // 2*E floats (edge_index as float)

    int*   wsi      = (int*)d_ws;
    int*   deg      = wsi + OFF_DEG;
    int*   rowstart = wsi + OFF_ROW;
    int*   partial  = wsi + OFF_PAR;
    int*   rank     = wsi + OFF_RANK;
    int*   csr      = wsi + OFF_CSR;
    float* pq       = (float*)d_ws + OFF_PQ;

    hipMemsetAsync(deg, 0, (size_t)NN * sizeof(int), stream);

    k_prep<<<2048, 256, 0, stream>>>(ei, deg, rank);
    k_scanA<<<NBLK, 256, 0, stream>>>(deg, partial);
    k_scanB<<<NBLK, 256, 0, stream>>>(deg, partial, rowstart);
    k_build<<<2048, 256, 0, stream>>>(ei, rowstart, rank, csr, edge_out);
    k_l1<<<1024, 256, 0, stream>>>(csr, rowstart, deg, x,
                                   W1l, b1, W1r, W2l, b2, W2r, pq);
    k_l2<<<(NN + 255) / 256, 256, 0, stream>>>(csr, rowstart, deg, pq, out);
}

// Round 5
// 257.405 us; speedup vs baseline: 4.1482x; 4.1482x over previous
//
#include <hip/hip_runtime.h>

#define NN 100000   // nodes
#define NE 1000000  // edges
#define FD 64       // feature dim
#define NB 8        // nodes per wave iteration in k_l1 (NN % NB == 0)
#define PAD 65      // padded weight row stride in LDS (bank-conflict-free b128)
#define NBLK 98     // scan blocks: ceil(NN/1024)

// ws layout (4-byte units):
//   deg      : [0, NN)              int
//   rowstart : [NN, 2NN)            int   (exclusive scan of deg)
//   partial  : [2NN, 2NN+128)       int   (scan block sums)
//   rank     : [2NN+128, +NE)       int   (edge rank within its dst row)
//   csr      : [2NN+128+NE, +NE)    int   (src ids grouped by dst)
//   pq       : [2NN+128+2NE, +4NN)  float (p0,p1,q0,q1 per node)
// total ~ 10.4 MB

#define OFF_DEG 0
#define OFF_ROW (NN)
#define OFF_PAR (2 * NN)
#define OFF_RANK (2 * NN + 128)
#define OFF_CSR (2 * NN + 128 + NE)
#define OFF_PQ  (2 * NN + 128 + 2 * NE)

// ---------------------------------------------------------------------------
// K1: in-degree counts + per-edge rank within its dst row.
__global__ void k_prep(const int* __restrict__ ei, int* __restrict__ deg,
                       int* __restrict__ rank) {
    int stride = gridDim.x * blockDim.x;
    for (int e = blockIdx.x * blockDim.x + threadIdx.x; e < NE; e += stride) {
        int d = ei[NE + e];
        rank[e] = atomicAdd(&deg[d], 1);
    }
}

// ---------------------------------------------------------------------------
// K2a: per-block (1024-elem) sums of deg -> partial[b]
__global__ __launch_bounds__(256) void k_scanA(const int* __restrict__ deg,
                                               int* __restrict__ partial) {
    __shared__ int lds[256];
    int t = threadIdx.x;
    int base = blockIdx.x * 1024 + t * 4;
    int s_t = 0;
    if (base < NN) {  // NN % 4 == 0
        int4 v = *(const int4*)(deg + base);
        s_t = v.x + v.y + v.z + v.w;
    }
    lds[t] = s_t;
    __syncthreads();
    for (int s = 128; s; s >>= 1) {
        if (t < s) lds[t] += lds[t + s];
        __syncthreads();
    }
    if (t == 0) partial[blockIdx.x] = lds[0];
}

// K2b: block offset + intra-block exclusive scan -> rowstart[i]
__global__ __launch_bounds__(256) void k_scanB(const int* __restrict__ deg,
                                               const int* __restrict__ partial,
                                               int* __restrict__ rowstart) {
    __shared__ int lds[256];
    int t = threadIdx.x, b = blockIdx.x;
    lds[t] = (t < b && t < NBLK) ? partial[t] : 0;
    __syncthreads();
    for (int s = 128; s; s >>= 1) {
        if (t < s) lds[t] += lds[t + s];
        __syncthreads();
    }
    int bo = lds[0];
    __syncthreads();

    int base = b * 1024 + t * 4;
    int4 v = make_int4(0, 0, 0, 0);
    if (base < NN) v = *(const int4*)(deg + base);
    int s_t = v.x + v.y + v.z + v.w;

    lds[t] = s_t;
    __syncthreads();
    for (int off = 1; off < 256; off <<= 1) {
        int v2 = lds[t];
        if (t >= off) v2 += lds[t - off];
        __syncthreads();
        lds[t] = v2;
        __syncthreads();
    }
    int excl = lds[t] - s_t;
    if (base < NN) {
        int r = bo + excl;
        int4 out;
        out.x = r;
        out.y = r + v.x;
        out.z = r + v.x + v.y;
        out.w = r + v.x + v.y + v.z;
        *(int4*)(rowstart + base) = out;
    }
}

// ---------------------------------------------------------------------------
// K3: pure scatter (no atomics): csr[rowstart[d]+rank[e]] = s; also emit
//     edge_index as float to the output tail.
__global__ void k_build(const int* __restrict__ ei, const int* __restrict__ rowstart,
                        const int* __restrict__ rank, int* __restrict__ csr,
                        float* __restrict__ edge_out) {
    int stride = gridDim.x * blockDim.x;
    for (int e = blockIdx.x * blockDim.x + threadIdx.x; e < NE; e += stride) {
        int s = ei[e];
        int d = ei[NE + e];
        edge_out[e] = (float)s;
        edge_out[NE + e] = (float)d;
        csr[rowstart[d] + rank[e]] = s;
    }
}

// ---------------------------------------------------------------------------
// K4: fused layer-1, NB nodes per wave iteration.
//  weights: staged ONCE per block into LDS (row-major, PAD=65 stride so
//    per-lane row reads are 2-way/free on the 32 banks). This keeps them out
//    of the register file (R4: compiler hoisted 128 VGPRs of weights -> spill).
//  phase A (per node): lane=feature mean-gather (8-way unrolled readlane for
//    scalar base addresses, 8 outstanding loads) -> LDS srow/xrow.
//  phase B: sweep weight rows from LDS; srow/xrow via wave-uniform broadcast
//    LDS reads; 8 nodes amortize each weight load.
//  phase C (per node): h=relu(...), wave-reduce h@W2^T -> pq[n] (float4).
__global__ __launch_bounds__(256) void k_l1(
    const int* __restrict__ csr, const int* __restrict__ rowstart,
    const int* __restrict__ deg, const float* __restrict__ x,
    const float* __restrict__ W1l, const float* __restrict__ b1,
    const float* __restrict__ W1r,
    const float* __restrict__ W2l, const float* __restrict__ b2,
    const float* __restrict__ W2r,
    float* __restrict__ pq) {
    __shared__ float wlds[2][FD][PAD];   // 33,280 B
    __shared__ float srow[4][NB][FD];    // 8 KB
    __shared__ float xrow[4][NB][FD];    // 8 KB
    const int lane = threadIdx.x & 63;
    const int wid = threadIdx.x >> 6;
    const int gw = (blockIdx.x * blockDim.x + threadIdx.x) >> 6;
    const int nwav = (gridDim.x * blockDim.x) >> 6;

    // stage weights once per block
    for (int i = threadIdx.x; i < FD * FD; i += 256) {
        int r = i >> 6, cc = i & 63;
        wlds[0][r][cc] = W1l[i];
        wlds[1][r][cc] = W1r[i];
    }
    __syncthreads();

    const float b1k = b1[lane];
    const float w2l0 = W2l[lane], w2l1 = W2l[FD + lane];
    const float w2r0 = W2r[lane], w2r1 = W2r[FD + lane];
    const float b20 = b2[0], b21 = b2[1];

    for (int c = gw; c < NN / NB; c += nwav) {
        const int base = c * NB;
        // ---- phase A: gather NB rows ----
#pragma unroll 1
        for (int nb = 0; nb < NB; ++nb) {
            const int n = base + nb;
            const int rs = rowstart[n];
            const int d = deg[n];
            const int dm = min(d, 64);
            int srcj = (lane < dm) ? csr[rs + lane] : 0;
            float acc0 = 0.f, acc1 = 0.f;
            int j = 0;
            for (; j + 8 <= dm; j += 8) {
                int s0 = __builtin_amdgcn_readlane(srcj, j);
                int s1 = __builtin_amdgcn_readlane(srcj, j + 1);
                int s2 = __builtin_amdgcn_readlane(srcj, j + 2);
                int s3 = __builtin_amdgcn_readlane(srcj, j + 3);
                int s4 = __builtin_amdgcn_readlane(srcj, j + 4);
                int s5 = __builtin_amdgcn_readlane(srcj, j + 5);
                int s6 = __builtin_amdgcn_readlane(srcj, j + 6);
                int s7 = __builtin_amdgcn_readlane(srcj, j + 7);
                float v0 = x[(size_t)s0 * FD + lane];
                float v1 = x[(size_t)s1 * FD + lane];
                float v2 = x[(size_t)s2 * FD + lane];
                float v3 = x[(size_t)s3 * FD + lane];
                float v4 = x[(size_t)s4 * FD + lane];
                float v5 = x[(size_t)s5 * FD + lane];
                float v6 = x[(size_t)s6 * FD + lane];
                float v7 = x[(size_t)s7 * FD + lane];
                acc0 += (v0 + v2) + (v4 + v6);
                acc1 += (v1 + v3) + (v5 + v7);
            }
            for (; j < dm; ++j) {
                int s0 = __builtin_amdgcn_readlane(srcj, j);
                acc0 += x[(size_t)s0 * FD + lane];
            }
            for (int e = rs + 64; e < rs + d; ++e)  // deg>64 tail (rare)
                acc1 += x[(size_t)csr[e] * FD + lane];
            float invc = 1.0f / (float)max(d, 1);
            srow[wid][nb][lane] = (acc0 + acc1) * invc;
            xrow[wid][nb][lane] = x[(size_t)n * FD + lane];
        }
        asm volatile("s_waitcnt lgkmcnt(0)" ::: "memory");

        // ---- phase B: weight sweep from LDS, amortized over NB nodes ----
        float accA[NB], accR[NB];
#pragma unroll
        for (int nb = 0; nb < NB; ++nb) { accA[nb] = 0.f; accR[nb] = 0.f; }
#pragma unroll 4
        for (int j4 = 0; j4 < FD / 4; ++j4) {
            const float4 wlv = *(const float4*)(&wlds[0][lane][4 * j4]);
            const float4 wrv = *(const float4*)(&wlds[1][lane][4 * j4]);
#pragma unroll
            for (int nb = 0; nb < NB; ++nb) {
                const float4 s = *(const float4*)(&srow[wid][nb][4 * j4]);   // broadcast
                const float4 xx = *(const float4*)(&xrow[wid][nb][4 * j4]);  // broadcast
                accA[nb] += s.x * wlv.x + s.y * wlv.y + s.z * wlv.z + s.w * wlv.w;
                accR[nb] += xx.x * wrv.x + xx.y * wrv.y + xx.z * wrv.z + xx.w * wrv.w;
            }
        }

        // ---- phase C: relu + projections + wave reductions ----
#pragma unroll 1
        for (int nb = 0; nb < NB; ++nb) {
            float h = fmaxf(accA[nb] + accR[nb] + b1k, 0.f);
            float p0 = h * w2l0, p1 = h * w2l1;
            float q0 = h * w2r0, q1 = h * w2r1;
#pragma unroll
            for (int off = 32; off; off >>= 1) {
                p0 += __shfl_xor(p0, off);
                p1 += __shfl_xor(p1, off);
                q0 += __shfl_xor(q0, off);
                q1 += __shfl_xor(q1, off);
            }
            if (lane == 0)
                *(float4*)(pq + 4 * (size_t)(base + nb)) =
                    make_float4(p0, p1, q0 + b20, q1 + b21);
        }
    }
}

// ---------------------------------------------------------------------------
// K5: layer-2 mean aggregation of p (8B gathers, L2/L3-resident) + final add.
__global__ void k_l2(const int* __restrict__ csr, const int* __restrict__ rowstart,
                     const int* __restrict__ deg, const float* __restrict__ pq,
                     float* __restrict__ out) {
    int n = blockIdx.x * blockDim.x + threadIdx.x;
    if (n >= NN) return;
    int rs = rowstart[n];
    int d = deg[n];
    float a0 = 0.f, a1 = 0.f, c0 = 0.f, c1 = 0.f;
    int i = 0;
    for (; i + 2 <= d; i += 2) {
        int s0 = csr[rs + i];
        int s1 = csr[rs + i + 1];
        float2 v0 = *(const float2*)(pq + 4 * (size_t)s0);
        float2 v1 = *(const float2*)(pq + 4 * (size_t)s1);
        a0 += v0.x; a1 += v0.y;
        c0 += v1.x; c1 += v1.y;
    }
    if (i < d) {
        int s0 = csr[rs + i];
        float2 v0 = *(const float2*)(pq + 4 * (size_t)s0);
        a0 += v0.x; a1 += v0.y;
    }
    float inv = 1.0f / (float)max(d, 1);
    float2 q = *(const float2*)(pq + 4 * (size_t)n + 2);
    *(float2*)(out + 2 * (size_t)n) =
        make_float2((a0 + c0) * inv + q.x, (a1 + c1) * inv + q.y);
}

// ---------------------------------------------------------------------------
extern "C" void kernel_launch(void* const* d_in, const int* in_sizes, int n_in,
                              void* d_out, int out_size, void* d_ws, size_t ws_size,
                              hipStream_t stream) {
    const float* x   = (const float*)d_in[0];
    const int*   ei  = (const int*)d_in[1];
    const float* W1l = (const float*)d_in[2];
    const float* b1  = (const float*)d_in[3];
    const float* W1r = (const float*)d_in[4];
    const float* W2l = (const float*)d_in[5];
    const float* b2  = (const float*)d_in[6];
    const float* W2r = (const float*)d_in[7];

    float* out      = (float*)d_out;   // N*2 floats
    float* edge_out = out + 2 * NN;    // 2*E floats (edge_index as float)

    int*   wsi      = (int*)d_ws;
    int*   deg      = wsi + OFF_DEG;
    int*   rowstart = wsi + OFF_ROW;
    int*   partial  = wsi + OFF_PAR;
    int*   rank     = wsi + OFF_RANK;
    int*   csr      = wsi + OFF_CSR;
    float* pq       = (float*)d_ws + OFF_PQ;

    hipMemsetAsync(deg, 0, (size_t)NN * sizeof(int), stream);

    k_prep<<<2048, 256, 0, stream>>>(ei, deg, rank);
    k_scanA<<<NBLK, 256, 0, stream>>>(deg, partial);
    k_scanB<<<NBLK, 256, 0, stream>>>(deg, partial, rowstart);
    k_build<<<2048, 256, 0, stream>>>(ei, rowstart, rank, csr, edge_out);
    k_l1<<<1024, 256, 0, stream>>>(csr, rowstart, deg, x,
                                   W1l, b1, W1r, W2l, b2, W2r, pq);
    k_l2<<<(NN + 255) / 256, 256, 0, stream>>>(csr, rowstart, deg, pq, out);
}

// Round 6
// 197.775 us; speedup vs baseline: 5.3989x; 1.3015x over previous
//
#include <hip/hip_runtime.h>

#define NN 100000   // nodes
#define NE 1000000  // edges
#define FD 64       // feature dim
#define CHK 64      // nodes per block tile in k_l1
#define NBLK 98     // scan blocks: ceil(NN/1024)

// ws layout (4-byte units):
//   deg      : [0, NN)              int
//   rowstart : [NN, 2NN)            int   (exclusive scan of deg)
//   partial  : [2NN, 2NN+128)       int   (scan block sums)
//   rank     : [2NN+128, +NE)       int   (edge rank within its dst row)
//   csr      : [2NN+128+NE, +NE)    int   (src ids grouped by dst)
//   pq       : [2NN+128+2NE, +4NN)  float (p0,p1,q0,q1 per node)
//   wt       : next, 2*4096 floats  (W1l^T, W1r^T: [j][k] layouts)
// total ~ 10.5 MB

#define OFF_DEG 0
#define OFF_ROW (NN)
#define OFF_PAR (2 * NN)
#define OFF_RANK (2 * NN + 128)
#define OFF_CSR (2 * NN + 128 + NE)
#define OFF_PQ  (2 * NN + 128 + 2 * NE)
#define OFF_WT  (2 * NN + 128 + 2 * NE + 4 * NN)

// ---------------------------------------------------------------------------
// K0: transpose layer-1 weights to [j][k] so phase B reads rows uniformly.
__global__ void k_wt(const float* __restrict__ W1l, const float* __restrict__ W1r,
                     float* __restrict__ wt1l, float* __restrict__ wt1r) {
    int i = blockIdx.x * blockDim.x + threadIdx.x;
    if (i < FD * FD) {
        int k = i >> 6, j = i & 63;
        wt1l[j * FD + k] = W1l[i];
        wt1r[j * FD + k] = W1r[i];
    }
}

// ---------------------------------------------------------------------------
// K1: in-degree counts + per-edge rank within its dst row.
__global__ void k_prep(const int* __restrict__ ei, int* __restrict__ deg,
                       int* __restrict__ rank) {
    int stride = gridDim.x * blockDim.x;
    for (int e = blockIdx.x * blockDim.x + threadIdx.x; e < NE; e += stride) {
        int d = ei[NE + e];
        rank[e] = atomicAdd(&deg[d], 1);
    }
}

// ---------------------------------------------------------------------------
// K2a: per-block (1024-elem) sums of deg -> partial[b]
__global__ __launch_bounds__(256) void k_scanA(const int* __restrict__ deg,
                                               int* __restrict__ partial) {
    __shared__ int lds[256];
    int t = threadIdx.x;
    int base = blockIdx.x * 1024 + t * 4;
    int s_t = 0;
    if (base < NN) {  // NN % 4 == 0
        int4 v = *(const int4*)(deg + base);
        s_t = v.x + v.y + v.z + v.w;
    }
    lds[t] = s_t;
    __syncthreads();
    for (int s = 128; s; s >>= 1) {
        if (t < s) lds[t] += lds[t + s];
        __syncthreads();
    }
    if (t == 0) partial[blockIdx.x] = lds[0];
}

// K2b: block offset + intra-block exclusive scan -> rowstart[i]
__global__ __launch_bounds__(256) void k_scanB(const int* __restrict__ deg,
                                               const int* __restrict__ partial,
                                               int* __restrict__ rowstart) {
    __shared__ int lds[256];
    int t = threadIdx.x, b = blockIdx.x;
    lds[t] = (t < b && t < NBLK) ? partial[t] : 0;
    __syncthreads();
    for (int s = 128; s; s >>= 1) {
        if (t < s) lds[t] += lds[t + s];
        __syncthreads();
    }
    int bo = lds[0];
    __syncthreads();

    int base = b * 1024 + t * 4;
    int4 v = make_int4(0, 0, 0, 0);
    if (base < NN) v = *(const int4*)(deg + base);
    int s_t = v.x + v.y + v.z + v.w;

    lds[t] = s_t;
    __syncthreads();
    for (int off = 1; off < 256; off <<= 1) {
        int v2 = lds[t];
        if (t >= off) v2 += lds[t - off];
        __syncthreads();
        lds[t] = v2;
        __syncthreads();
    }
    int excl = lds[t] - s_t;
    if (base < NN) {
        int r = bo + excl;
        int4 out;
        out.x = r;
        out.y = r + v.x;
        out.z = r + v.x + v.y;
        out.w = r + v.x + v.y + v.z;
        *(int4*)(rowstart + base) = out;
    }
}

// ---------------------------------------------------------------------------
// K3: pure scatter (no atomics): csr[rowstart[d]+rank[e]] = s; also emit
//     edge_index as float to the output tail.
__global__ void k_build(const int* __restrict__ ei, const int* __restrict__ rowstart,
                        const int* __restrict__ rank, int* __restrict__ csr,
                        float* __restrict__ edge_out) {
    int stride = gridDim.x * blockDim.x;
    for (int e = blockIdx.x * blockDim.x + threadIdx.x; e < NE; e += stride) {
        int s = ei[e];
        int d = ei[NE + e];
        edge_out[e] = (float)s;
        edge_out[NE + e] = (float)d;
        csr[rowstart[d] + rank[e]] = s;
    }
}

// ---------------------------------------------------------------------------
// K4: fused layer-1, one 64-node tile per block (4 waves).
//  phase A: wave w gathers node rows [16w,16w+16) (lane=feature, readlane
//    batches) -> srow/xrow[64][65] (mean pre-scaled).
//  phase B: lane=local-node, wave=16-wide k-slice. h[16] in registers; per j:
//    2 conflict-free ds_read_b32 + uniform loads of transposed weights.
//    relu + W2 projections fold in per-lane (NO shuffle reductions);
//    cross-wave combine via 4 LDS float atomics per lane.
__global__ __launch_bounds__(256, 4) void k_l1(
    const int* __restrict__ csr, const int* __restrict__ rowstart,
    const int* __restrict__ deg, const float* __restrict__ x,
    const float* __restrict__ wt1l, const float* __restrict__ b1,
    const float* __restrict__ wt1r,
    const float* __restrict__ W2l, const float* __restrict__ b2,
    const float* __restrict__ W2r,
    float* __restrict__ pq) {
    __shared__ float srow[CHK][FD + 1];
    __shared__ float xrow[CHK][FD + 1];
    __shared__ float pacc[CHK * 4];
    const int lane = threadIdx.x & 63;
    const int wid = threadIdx.x >> 6;
    const int base = blockIdx.x * CHK;

    pacc[threadIdx.x] = 0.f;

    // ---- phase A: gather 16 node rows per wave ----
    for (int i = 0; i < 16; ++i) {
        const int nl = wid * 16 + i;
        const int n = base + nl;
        if (n >= NN) break;
        const int rs = rowstart[n];
        const int d = deg[n];
        const int dm = min(d, 64);
        int srcj = (lane < dm) ? csr[rs + lane] : 0;
        float acc0 = 0.f, acc1 = 0.f;
        int j = 0;
        for (; j + 8 <= dm; j += 8) {
            int s0 = __builtin_amdgcn_readlane(srcj, j);
            int s1 = __builtin_amdgcn_readlane(srcj, j + 1);
            int s2 = __builtin_amdgcn_readlane(srcj, j + 2);
            int s3 = __builtin_amdgcn_readlane(srcj, j + 3);
            int s4 = __builtin_amdgcn_readlane(srcj, j + 4);
            int s5 = __builtin_amdgcn_readlane(srcj, j + 5);
            int s6 = __builtin_amdgcn_readlane(srcj, j + 6);
            int s7 = __builtin_amdgcn_readlane(srcj, j + 7);
            float v0 = x[(size_t)s0 * FD + lane];
            float v1 = x[(size_t)s1 * FD + lane];
            float v2 = x[(size_t)s2 * FD + lane];
            float v3 = x[(size_t)s3 * FD + lane];
            float v4 = x[(size_t)s4 * FD + lane];
            float v5 = x[(size_t)s5 * FD + lane];
            float v6 = x[(size_t)s6 * FD + lane];
            float v7 = x[(size_t)s7 * FD + lane];
            acc0 += (v0 + v2) + (v4 + v6);
            acc1 += (v1 + v3) + (v5 + v7);
        }
        for (; j < dm; ++j) {
            int s0 = __builtin_amdgcn_readlane(srcj, j);
            acc0 += x[(size_t)s0 * FD + lane];
        }
        for (int e = rs + 64; e < rs + d; ++e)  // deg>64 tail (rare)
            acc1 += x[(size_t)csr[e] * FD + lane];
        float invc = 1.0f / (float)max(d, 1);
        srow[nl][lane] = (acc0 + acc1) * invc;
        xrow[nl][lane] = x[(size_t)n * FD + lane];
    }
    __syncthreads();

    // ---- phase B: lane = node, this wave covers k in [kbase, kbase+16) ----
    const int kbase = __builtin_amdgcn_readfirstlane(wid * 16);
    float4 h0 = *(const float4*)(b1 + kbase);
    float4 h1 = *(const float4*)(b1 + kbase + 4);
    float4 h2 = *(const float4*)(b1 + kbase + 8);
    float4 h3 = *(const float4*)(b1 + kbase + 12);
    const float* sr = &srow[lane][0];
    const float* xr = &xrow[lane][0];

#pragma unroll 2
    for (int j = 0; j < FD; ++j) {
        const float sj = sr[j];
        const float xj = xr[j];
        const float* wl = wt1l + j * FD + kbase;
        const float* wr = wt1r + j * FD + kbase;
        const float4 a0 = *(const float4*)(wl);
        const float4 a1 = *(const float4*)(wl + 4);
        const float4 a2 = *(const float4*)(wl + 8);
        const float4 a3 = *(const float4*)(wl + 12);
        const float4 c0 = *(const float4*)(wr);
        const float4 c1 = *(const float4*)(wr + 4);
        const float4 c2 = *(const float4*)(wr + 8);
        const float4 c3 = *(const float4*)(wr + 12);
        h0.x += sj * a0.x + xj * c0.x;  h0.y += sj * a0.y + xj * c0.y;
        h0.z += sj * a0.z + xj * c0.z;  h0.w += sj * a0.w + xj * c0.w;
        h1.x += sj * a1.x + xj * c1.x;  h1.y += sj * a1.y + xj * c1.y;
        h1.z += sj * a1.z + xj * c1.z;  h1.w += sj * a1.w + xj * c1.w;
        h2.x += sj * a2.x + xj * c2.x;  h2.y += sj * a2.y + xj * c2.y;
        h2.z += sj * a2.z + xj * c2.z;  h2.w += sj * a2.w + xj * c2.w;
        h3.x += sj * a3.x + xj * c3.x;  h3.y += sj * a3.y + xj * c3.y;
        h3.z += sj * a3.z + xj * c3.z;  h3.w += sj * a3.w + xj * c3.w;
    }

    // ---- relu + W2 projections (per-lane, no shuffles) ----
    float p0 = 0.f, p1 = 0.f, q0 = 0.f, q1 = 0.f;
    {
        float hv[16] = {h0.x, h0.y, h0.z, h0.w, h1.x, h1.y, h1.z, h1.w,
                        h2.x, h2.y, h2.z, h2.w, h3.x, h3.y, h3.z, h3.w};
#pragma unroll
        for (int i4 = 0; i4 < 4; ++i4) {
            const float4 wa = *(const float4*)(W2l + kbase + 4 * i4);
            const float4 wb = *(const float4*)(W2l + FD + kbase + 4 * i4);
            const float4 wc = *(const float4*)(W2r + kbase + 4 * i4);
            const float4 wd = *(const float4*)(W2r + FD + kbase + 4 * i4);
            float r0 = fmaxf(hv[4 * i4 + 0], 0.f);
            float r1 = fmaxf(hv[4 * i4 + 1], 0.f);
            float r2 = fmaxf(hv[4 * i4 + 2], 0.f);
            float r3 = fmaxf(hv[4 * i4 + 3], 0.f);
            p0 += r0 * wa.x + r1 * wa.y + r2 * wa.z + r3 * wa.w;
            p1 += r0 * wb.x + r1 * wb.y + r2 * wb.z + r3 * wb.w;
            q0 += r0 * wc.x + r1 * wc.y + r2 * wc.z + r3 * wc.w;
            q1 += r0 * wd.x + r1 * wd.y + r2 * wd.z + r3 * wd.w;
        }
    }
    atomicAdd(&pacc[lane * 4 + 0], p0);
    atomicAdd(&pacc[lane * 4 + 1], p1);
    atomicAdd(&pacc[lane * 4 + 2], q0);
    atomicAdd(&pacc[lane * 4 + 3], q1);
    __syncthreads();

    // ---- write pq: thread t -> (node t>>2, comp t&3), coalesced ----
    {
        const int t = threadIdx.x;
        const int n = base + (t >> 2);
        if (n < NN) {
            float v = pacc[t];
            const int c = t & 3;
            if (c == 2) v += b2[0];
            if (c == 3) v += b2[1];
            pq[(size_t)n * 4 + c] = v;
        }
    }
}

// ---------------------------------------------------------------------------
// K5: layer-2 mean aggregation of p (8B gathers, L2/L3-resident) + final add.
__global__ void k_l2(const int* __restrict__ csr, const int* __restrict__ rowstart,
                     const int* __restrict__ deg, const float* __restrict__ pq,
                     float* __restrict__ out) {
    int n = blockIdx.x * blockDim.x + threadIdx.x;
    if (n >= NN) return;
    int rs = rowstart[n];
    int d = deg[n];
    float a0 = 0.f, a1 = 0.f, c0 = 0.f, c1 = 0.f;
    int i = 0;
    for (; i + 2 <= d; i += 2) {
        int s0 = csr[rs + i];
        int s1 = csr[rs + i + 1];
        float2 v0 = *(const float2*)(pq + 4 * (size_t)s0);
        float2 v1 = *(const float2*)(pq + 4 * (size_t)s1);
        a0 += v0.x; a1 += v0.y;
        c0 += v1.x; c1 += v1.y;
    }
    if (i < d) {
        int s0 = csr[rs + i];
        float2 v0 = *(const float2*)(pq + 4 * (size_t)s0);
        a0 += v0.x; a1 += v0.y;
    }
    float inv = 1.0f / (float)max(d, 1);
    float2 q = *(const float2*)(pq + 4 * (size_t)n + 2);
    *(float2*)(out + 2 * (size_t)n) =
        make_float2((a0 + c0) * inv + q.x, (a1 + c1) * inv + q.y);
}

// ---------------------------------------------------------------------------
extern "C" void kernel_launch(void* const* d_in, const int* in_sizes, int n_in,
                              void* d_out, int out_size, void* d_ws, size_t ws_size,
                              hipStream_t stream) {
    const float* x   = (const float*)d_in[0];
    const int*   ei  = (const int*)d_in[1];
    const float* W1l = (const float*)d_in[2];
    const float* b1  = (const float*)d_in[3];
    const float* W1r = (const float*)d_in[4];
    const float* W2l = (const float*)d_in[5];
    const float* b2  = (const float*)d_in[6];
    const float* W2r = (const float*)d_in[7];

    float* out      = (float*)d_out;   // N*2 floats
    float* edge_out = out + 2 * NN;    // 2*E floats (edge_index as float)

    int*   wsi      = (int*)d_ws;
    int*   deg      = wsi + OFF_DEG;
    int*   rowstart = wsi + OFF_ROW;
    int*   partial  = wsi + OFF_PAR;
    int*   rank     = wsi + OFF_RANK;
    int*   csr      = wsi + OFF_CSR;
    float* pq       = (float*)d_ws + OFF_PQ;
    float* wt1l     = (float*)d_ws + OFF_WT;
    float* wt1r     = wt1l + FD * FD;

    hipMemsetAsync(deg, 0, (size_t)NN * sizeof(int), stream);

    k_wt<<<16, 256, 0, stream>>>(W1l, W1r, wt1l, wt1r);
    k_prep<<<2048, 256, 0, stream>>>(ei, deg, rank);
    k_scanA<<<NBLK, 256, 0, stream>>>(deg, partial);
    k_scanB<<<NBLK, 256, 0, stream>>>(deg, partial, rowstart);
    k_build<<<2048, 256, 0, stream>>>(ei, rowstart, rank, csr, edge_out);
    k_l1<<<(NN + CHK - 1) / CHK, 256, 0, stream>>>(csr, rowstart, deg, x,
                                                   wt1l, b1, wt1r,
                                                   W2l, b2, W2r, pq);
    k_l2<<<(NN + 255) / 256, 256, 0, stream>>>(csr, rowstart, deg, pq, out);
}

// Round 7
// 195.785 us; speedup vs baseline: 5.4537x; 1.0102x over previous
//
#include <hip/hip_runtime.h>

#define NN 100000   // nodes
#define NE 1000000  // edges
#define FD 64       // feature dim
#define CHK 64      // nodes per block tile in k_l1
#define RST 131     // rowbuf stride: (131*n+j)%32=(3n+j)%32 -> 2-way, free
#define NBLK 98     // scan blocks: ceil(NN/1024)

// ws layout (4-byte units):
//   deg      : [0, NN)              int
//   rowstart : [NN, 2NN)            int   (exclusive scan of deg)
//   partial  : [2NN, 2NN+128)       int   (scan block sums)
//   rank     : [2NN+128, +NE)       int   (edge rank within its dst row)
//   csr      : [2NN+128+NE, +NE)    int   (src ids grouped by dst)
//   pq       : [2NN+128+2NE, +4NN)  float (p0,p1,q0,q1 per node)
//   wt       : next, 2*4096 floats  (W1l^T, W1r^T: [j][k] layouts)
// total ~ 10.5 MB

#define OFF_DEG 0
#define OFF_ROW (NN)
#define OFF_PAR (2 * NN)
#define OFF_RANK (2 * NN + 128)
#define OFF_CSR (2 * NN + 128 + NE)
#define OFF_PQ  (2 * NN + 128 + 2 * NE)
#define OFF_WT  (2 * NN + 128 + 2 * NE + 4 * NN)

// ---------------------------------------------------------------------------
// K0: transpose layer-1 weights to [j][k] so phase B reads rows uniformly.
__global__ void k_wt(const float* __restrict__ W1l, const float* __restrict__ W1r,
                     float* __restrict__ wt1l, float* __restrict__ wt1r) {
    int i = blockIdx.x * blockDim.x + threadIdx.x;
    if (i < FD * FD) {
        int k = i >> 6, j = i & 63;
        wt1l[j * FD + k] = W1l[i];
        wt1r[j * FD + k] = W1r[i];
    }
}

// ---------------------------------------------------------------------------
// K1: in-degree counts + per-edge rank within its dst row.
__global__ void k_prep(const int* __restrict__ ei, int* __restrict__ deg,
                       int* __restrict__ rank) {
    int stride = gridDim.x * blockDim.x;
    for (int e = blockIdx.x * blockDim.x + threadIdx.x; e < NE; e += stride) {
        int d = ei[NE + e];
        rank[e] = atomicAdd(&deg[d], 1);
    }
}

// ---------------------------------------------------------------------------
// K2a: per-block (1024-elem) sums of deg -> partial[b]
__global__ __launch_bounds__(256) void k_scanA(const int* __restrict__ deg,
                                               int* __restrict__ partial) {
    __shared__ int lds[256];
    int t = threadIdx.x;
    int base = blockIdx.x * 1024 + t * 4;
    int s_t = 0;
    if (base < NN) {  // NN % 4 == 0
        int4 v = *(const int4*)(deg + base);
        s_t = v.x + v.y + v.z + v.w;
    }
    lds[t] = s_t;
    __syncthreads();
    for (int s = 128; s; s >>= 1) {
        if (t < s) lds[t] += lds[t + s];
        __syncthreads();
    }
    if (t == 0) partial[blockIdx.x] = lds[0];
}

// K2b: block offset + intra-block exclusive scan -> rowstart[i]
__global__ __launch_bounds__(256) void k_scanB(const int* __restrict__ deg,
                                               const int* __restrict__ partial,
                                               int* __restrict__ rowstart) {
    __shared__ int lds[256];
    int t = threadIdx.x, b = blockIdx.x;
    lds[t] = (t < b && t < NBLK) ? partial[t] : 0;
    __syncthreads();
    for (int s = 128; s; s >>= 1) {
        if (t < s) lds[t] += lds[t + s];
        __syncthreads();
    }
    int bo = lds[0];
    __syncthreads();

    int base = b * 1024 + t * 4;
    int4 v = make_int4(0, 0, 0, 0);
    if (base < NN) v = *(const int4*)(deg + base);
    int s_t = v.x + v.y + v.z + v.w;

    lds[t] = s_t;
    __syncthreads();
    for (int off = 1; off < 256; off <<= 1) {
        int v2 = lds[t];
        if (t >= off) v2 += lds[t - off];
        __syncthreads();
        lds[t] = v2;
        __syncthreads();
    }
    int excl = lds[t] - s_t;
    if (base < NN) {
        int r = bo + excl;
        int4 out;
        out.x = r;
        out.y = r + v.x;
        out.z = r + v.x + v.y;
        out.w = r + v.x + v.y + v.z;
        *(int4*)(rowstart + base) = out;
    }
}

// ---------------------------------------------------------------------------
// K3: pure scatter (no atomics): csr[rowstart[d]+rank[e]] = s; also emit
//     edge_index as float to the output tail.
__global__ void k_build(const int* __restrict__ ei, const int* __restrict__ rowstart,
                        const int* __restrict__ rank, int* __restrict__ csr,
                        float* __restrict__ edge_out) {
    int stride = gridDim.x * blockDim.x;
    for (int e = blockIdx.x * blockDim.x + threadIdx.x; e < NE; e += stride) {
        int s = ei[e];
        int d = ei[NE + e];
        edge_out[e] = (float)s;
        edge_out[NE + e] = (float)d;
        csr[rowstart[d] + rank[e]] = s;
    }
}

// ---------------------------------------------------------------------------
// K4: fused layer-1, one 64-node tile per block (8 waves, 512 threads).
//  phase A: wave w gathers rows [8w, 8w+8) in PAIRS, fully-predicated 8-wide
//    batches (clamped readlane index; masked lanes re-read the last neighbor
//    row -> L1 hit). 16 loads in flight per wave, no serial singles.
//  phase B: lane = node, wave w covers k-slice [8w, 8w+8). h[8] in registers;
//    per j: ds_read2-able (sj,xj) from rowbuf + uniform (scalar) loads of
//    transposed weights; relu + W2 fold per-lane; cross-wave combine via LDS
//    atomics. No shuffle reductions.
__global__ __launch_bounds__(512, 8) void k_l1(
    const int* __restrict__ csr, const int* __restrict__ rowstart,
    const int* __restrict__ deg, const float* __restrict__ x,
    const float* __restrict__ wt1l, const float* __restrict__ b1,
    const float* __restrict__ wt1r,
    const float* __restrict__ W2l, const float* __restrict__ b2,
    const float* __restrict__ W2r,
    float* __restrict__ pq) {
    __shared__ float rowbuf[CHK][RST];   // [n][0..63]=aggr, [n][65..128]=x row
    __shared__ float pacc[4 * CHK];
    const int lane = threadIdx.x & 63;
    const int wid = threadIdx.x >> 6;    // 0..7
    const int base = blockIdx.x * CHK;

    if (threadIdx.x < 4 * CHK) pacc[threadIdx.x] = 0.f;

    // ---- phase A: 4 row-pairs per wave ----
    for (int i = 0; i < 8; i += 2) {
        const int nl0 = wid * 8 + i, nl1 = nl0 + 1;
        const int n0 = base + nl0, n1 = base + nl1;
        const bool ok0 = n0 < NN, ok1 = n1 < NN;
        const int rs0 = ok0 ? rowstart[n0] : 0;
        const int d0 = ok0 ? deg[n0] : 0;
        const int rs1 = ok1 ? rowstart[n1] : 0;
        const int d1 = ok1 ? deg[n1] : 0;
        const int dm0 = min(d0, 64), dm1 = min(d1, 64);
        const float xv0 = ok0 ? x[(size_t)n0 * FD + lane] : 0.f;
        const float xv1 = ok1 ? x[(size_t)n1 * FD + lane] : 0.f;
        int a0v = (dm0 > 0) ? csr[rs0 + min(lane, dm0 - 1)] : 0;
        int a1v = (dm1 > 0) ? csr[rs1 + min(lane, dm1 - 1)] : 0;
        float acc0 = 0.f, acc1 = 0.f;
        const int jmax = max(dm0, dm1);
        for (int j = 0; j < jmax; j += 8) {
#pragma unroll
            for (int t = 0; t < 8; ++t) {
                const int jt = j + t;
                const int i0 = jt < dm0 ? jt : (dm0 > 0 ? dm0 - 1 : 0);
                const int i1 = jt < dm1 ? jt : (dm1 > 0 ? dm1 - 1 : 0);
                const int s0 = __builtin_amdgcn_readlane(a0v, i0);
                const int s1 = __builtin_amdgcn_readlane(a1v, i1);
                const float v0 = x[(size_t)s0 * FD + lane];
                const float v1 = x[(size_t)s1 * FD + lane];
                acc0 += (jt < dm0) ? v0 : 0.f;   // uniform cndmask
                acc1 += (jt < dm1) ? v1 : 0.f;
            }
        }
        for (int e = rs0 + 64; e < rs0 + d0; ++e)  // deg>64 tail (rare)
            acc0 += x[(size_t)csr[e] * FD + lane];
        for (int e = rs1 + 64; e < rs1 + d1; ++e)
            acc1 += x[(size_t)csr[e] * FD + lane];
        if (ok0) {
            rowbuf[nl0][lane] = acc0 / (float)max(d0, 1);
            rowbuf[nl0][65 + lane] = xv0;
        }
        if (ok1) {
            rowbuf[nl1][lane] = acc1 / (float)max(d1, 1);
            rowbuf[nl1][65 + lane] = xv1;
        }
    }
    __syncthreads();

    // ---- phase B: lane = node, k-slice [kbase, kbase+8) ----
    const int kbase = __builtin_amdgcn_readfirstlane(wid * 8);
    float h[8];
#pragma unroll
    for (int t = 0; t < 8; ++t) h[t] = b1[kbase + t];
    const float* sr = &rowbuf[lane][0];
#pragma unroll 4
    for (int j = 0; j < FD; ++j) {
        const float sj = sr[j];
        const float xj = sr[65 + j];
        const float* wl = wt1l + j * FD + kbase;
        const float* wr = wt1r + j * FD + kbase;
#pragma unroll
        for (int t = 0; t < 8; ++t) h[t] += sj * wl[t] + xj * wr[t];
    }

    float p0 = 0.f, p1 = 0.f, q0 = 0.f, q1 = 0.f;
#pragma unroll
    for (int t = 0; t < 8; ++t) {
        const float r = fmaxf(h[t], 0.f);
        p0 += r * W2l[kbase + t];
        p1 += r * W2l[FD + kbase + t];
        q0 += r * W2r[kbase + t];
        q1 += r * W2r[FD + kbase + t];
    }
    atomicAdd(&pacc[0 * CHK + lane], p0);
    atomicAdd(&pacc[1 * CHK + lane], p1);
    atomicAdd(&pacc[2 * CHK + lane], q0);
    atomicAdd(&pacc[3 * CHK + lane], q1);
    __syncthreads();

    // ---- write pq: thread t -> (node t>>2, comp t&3), coalesced ----
    {
        const int t = threadIdx.x;
        if (t < 4 * CHK) {
            const int n = base + (t >> 2);
            if (n < NN) {
                const int c = t & 3;
                float v = pacc[c * CHK + (t >> 2)];
                if (c == 2) v += b2[0];
                if (c == 3) v += b2[1];
                pq[(size_t)n * 4 + c] = v;
            }
        }
    }
}

// ---------------------------------------------------------------------------
// K5: layer-2 mean aggregation of p + final add. 16 lanes per node,
//     4 nodes per wave (the old thread-per-node version was parallelism-
//     starved: 391 blocks ~ 1.5 blocks/CU).
__global__ void k_l2(const int* __restrict__ csr, const int* __restrict__ rowstart,
                     const int* __restrict__ deg, const float* __restrict__ pq,
                     float* __restrict__ out) {
    const int gw = (blockIdx.x * blockDim.x + threadIdx.x) >> 6;
    const int lane = threadIdx.x & 63;
    const int sub = lane >> 4;   // node within wave
    const int sl = lane & 15;    // lane within 16-group
    const int n = gw * 4 + sub;
    if (n >= NN) return;
    const int rs = rowstart[n];
    const int d = deg[n];
    float a0 = 0.f, a1 = 0.f;
    for (int i = sl; i < d; i += 16) {
        const int s = csr[rs + i];
        const float2 v = *(const float2*)(pq + 4 * (size_t)s);
        a0 += v.x;
        a1 += v.y;
    }
#pragma unroll
    for (int off = 8; off; off >>= 1) {
        a0 += __shfl_xor(a0, off);
        a1 += __shfl_xor(a1, off);
    }
    if (sl == 0) {
        const float inv = 1.0f / (float)max(d, 1);
        const float2 q = *(const float2*)(pq + 4 * (size_t)n + 2);
        *(float2*)(out + 2 * (size_t)n) = make_float2(a0 * inv + q.x, a1 * inv + q.y);
    }
}

// ---------------------------------------------------------------------------
extern "C" void kernel_launch(void* const* d_in, const int* in_sizes, int n_in,
                              void* d_out, int out_size, void* d_ws, size_t ws_size,
                              hipStream_t stream) {
    const float* x   = (const float*)d_in[0];
    const int*   ei  = (const int*)d_in[1];
    const float* W1l = (const float*)d_in[2];
    const float* b1  = (const float*)d_in[3];
    const float* W1r = (const float*)d_in[4];
    const float* W2l = (const float*)d_in[5];
    const float* b2  = (const float*)d_in[6];
    const float* W2r = (const float*)d_in[7];

    float* out      = (float*)d_out;   // N*2 floats
    float* edge_out = out + 2 * NN;    // 2*E floats (edge_index as float)

    int*   wsi      = (int*)d_ws;
    int*   deg      = wsi + OFF_DEG;
    int*   rowstart = wsi + OFF_ROW;
    int*   partial  = wsi + OFF_PAR;
    int*   rank     = wsi + OFF_RANK;
    int*   csr      = wsi + OFF_CSR;
    float* pq       = (float*)d_ws + OFF_PQ;
    float* wt1l     = (float*)d_ws + OFF_WT;
    float* wt1r     = wt1l + FD * FD;

    hipMemsetAsync(deg, 0, (size_t)NN * sizeof(int), stream);

    k_wt<<<16, 256, 0, stream>>>(W1l, W1r, wt1l, wt1r);
    k_prep<<<2048, 256, 0, stream>>>(ei, deg, rank);
    k_scanA<<<NBLK, 256, 0, stream>>>(deg, partial);
    k_scanB<<<NBLK, 256, 0, stream>>>(deg, partial, rowstart);
    k_build<<<2048, 256, 0, stream>>>(ei, rowstart, rank, csr, edge_out);
    k_l1<<<(NN + CHK - 1) / CHK, 512, 0, stream>>>(csr, rowstart, deg, x,
                                                   wt1l, b1, wt1r,
                                                   W2l, b2, W2r, pq);
    k_l2<<<((NN + 3) / 4 * 64 + 255) / 256, 256, 0, stream>>>(
        csr, rowstart, deg, pq, out);
}

// Round 8
// 168.353 us; speedup vs baseline: 6.3424x; 1.1629x over previous
//
#include <hip/hip_runtime.h>

#define NN 100000   // nodes
#define NE 1000000  // edges
#define FD 64       // feature dim
#define CHK 64      // nodes per block tile in k_l1
#define NBLK 98     // scan blocks: ceil(NN/1024)

// ws layout (4-byte units):
//   deg      : [0, NN)              int
//   rowstart : [NN, 2NN)            int   (exclusive scan of deg)
//   partial  : [2NN, 2NN+128)       int   (scan block sums)
//   rank     : [2NN+128, +NE)       int   (edge rank within its dst row)
//   csr      : [2NN+128+NE, +NE)    int   (src ids grouped by dst)
//   pq       : [2NN+128+2NE, +4NN)  float (p0,p1,q0,q1 per node)
//   wt       : next, 2*4096 floats  (W1l^T, W1r^T: [j][k] layouts)
// total ~ 10.5 MB

#define OFF_DEG 0
#define OFF_ROW (NN)
#define OFF_PAR (2 * NN)
#define OFF_RANK (2 * NN + 128)
#define OFF_CSR (2 * NN + 128 + NE)
#define OFF_PQ  (2 * NN + 128 + 2 * NE)
#define OFF_WT  (2 * NN + 128 + 2 * NE + 4 * NN)

// ---------------------------------------------------------------------------
// K0: transpose layer-1 weights to [j][k] so phase B reads rows uniformly.
__global__ void k_wt(const float* __restrict__ W1l, const float* __restrict__ W1r,
                     float* __restrict__ wt1l, float* __restrict__ wt1r) {
    int i = blockIdx.x * blockDim.x + threadIdx.x;
    if (i < FD * FD) {
        int k = i >> 6, j = i & 63;
        wt1l[j * FD + k] = W1l[i];
        wt1r[j * FD + k] = W1r[i];
    }
}

// ---------------------------------------------------------------------------
// K1: in-degree counts + per-edge rank within its dst row.
__global__ void k_prep(const int* __restrict__ ei, int* __restrict__ deg,
                       int* __restrict__ rank) {
    int stride = gridDim.x * blockDim.x;
    for (int e = blockIdx.x * blockDim.x + threadIdx.x; e < NE; e += stride) {
        int d = ei[NE + e];
        rank[e] = atomicAdd(&deg[d], 1);
    }
}

// ---------------------------------------------------------------------------
// K2a: per-block (1024-elem) sums of deg -> partial[b]
__global__ __launch_bounds__(256) void k_scanA(const int* __restrict__ deg,
                                               int* __restrict__ partial) {
    __shared__ int lds[256];
    int t = threadIdx.x;
    int base = blockIdx.x * 1024 + t * 4;
    int s_t = 0;
    if (base < NN) {  // NN % 4 == 0
        int4 v = *(const int4*)(deg + base);
        s_t = v.x + v.y + v.z + v.w;
    }
    lds[t] = s_t;
    __syncthreads();
    for (int s = 128; s; s >>= 1) {
        if (t < s) lds[t] += lds[t + s];
        __syncthreads();
    }
    if (t == 0) partial[blockIdx.x] = lds[0];
}

// K2b: block offset + intra-block exclusive scan -> rowstart[i]
__global__ __launch_bounds__(256) void k_scanB(const int* __restrict__ deg,
                                               const int* __restrict__ partial,
                                               int* __restrict__ rowstart) {
    __shared__ int lds[256];
    int t = threadIdx.x, b = blockIdx.x;
    lds[t] = (t < b && t < NBLK) ? partial[t] : 0;
    __syncthreads();
    for (int s = 128; s; s >>= 1) {
        if (t < s) lds[t] += lds[t + s];
        __syncthreads();
    }
    int bo = lds[0];
    __syncthreads();

    int base = b * 1024 + t * 4;
    int4 v = make_int4(0, 0, 0, 0);
    if (base < NN) v = *(const int4*)(deg + base);
    int s_t = v.x + v.y + v.z + v.w;

    lds[t] = s_t;
    __syncthreads();
    for (int off = 1; off < 256; off <<= 1) {
        int v2 = lds[t];
        if (t >= off) v2 += lds[t - off];
        __syncthreads();
        lds[t] = v2;
        __syncthreads();
    }
    int excl = lds[t] - s_t;
    if (base < NN) {
        int r = bo + excl;
        int4 out;
        out.x = r;
        out.y = r + v.x;
        out.z = r + v.x + v.y;
        out.w = r + v.x + v.y + v.z;
        *(int4*)(rowstart + base) = out;
    }
}

// ---------------------------------------------------------------------------
// K3: pure scatter (no atomics): csr[rowstart[d]+rank[e]] = s; also emit
//     edge_index as float to the output tail.
__global__ void k_build(const int* __restrict__ ei, const int* __restrict__ rowstart,
                        const int* __restrict__ rank, int* __restrict__ csr,
                        float* __restrict__ edge_out) {
    int stride = gridDim.x * blockDim.x;
    for (int e = blockIdx.x * blockDim.x + threadIdx.x; e < NE; e += stride) {
        int s = ei[e];
        int d = ei[NE + e];
        edge_out[e] = (float)s;
        edge_out[NE + e] = (float)d;
        csr[rowstart[d] + rank[e]] = s;
    }
}

// ---------------------------------------------------------------------------
// K4: fused layer-1, one 64-node tile per block (8 waves, 512 threads).
//  phase A: wave splits into 4 groups of 16 lanes; each group owns one node
//    and fetches whole 256B neighbor rows as float4 (16 lanes x 16B) -> one
//    wave-instruction gathers 4 rows (1KB). Neighbor ids: one coalesced
//    64-id load per 16-step chunk + group-internal __shfl broadcast.
//    Results written TRANSPOSED to sT/xT[j][n] (stride 65: writes (4sl+g+c)%32
//    = 2-way free; phase-B reads (j+lane)%32 = 2-way free).
//  phase B: lane = node, wave w covers k-slice [8w, 8w+8). h[8] in registers;
//    per j: 2 ds_read_b32 + uniform (scalar) loads of transposed weights;
//    relu + W2 fold per-lane; cross-wave combine via LDS atomics.
__global__ __launch_bounds__(512, 4) void k_l1(
    const int* __restrict__ csr, const int* __restrict__ rowstart,
    const int* __restrict__ deg, const float* __restrict__ x,
    const float* __restrict__ wt1l, const float* __restrict__ b1,
    const float* __restrict__ wt1r,
    const float* __restrict__ W2l, const float* __restrict__ b2,
    const float* __restrict__ W2r,
    float* __restrict__ pq) {
    __shared__ float sT[FD][CHK + 1];   // aggr, transposed   16.6 KB
    __shared__ float xT[FD][CHK + 1];   // self x, transposed 16.6 KB
    __shared__ float pacc[4 * CHK];     // 1 KB
    const int lane = threadIdx.x & 63;
    const int wid = threadIdx.x >> 6;   // 0..7
    const int g = lane >> 4;            // group 0..3
    const int sl = lane & 15;           // lane within group
    const int gb = g << 4;              // group base lane
    const int base = blockIdx.x * CHK;

    if (threadIdx.x < 4 * CHK) pacc[threadIdx.x] = 0.f;

    // ---- phase A: 2 rounds x 4 nodes per wave ----
    for (int r = 0; r < 2; ++r) {
        const int nl = wid * 8 + r * 4 + g;  // 0..63
        const int n = base + nl;
        const bool ok = n < NN;
        const int nn = ok ? n : NN - 1;
        const int d = deg[nn];               // group-uniform
        const int rs = rowstart[nn];
        const float4 xv = *(const float4*)(x + (size_t)nn * FD + sl * 4);
        float4 acc = make_float4(0.f, 0.f, 0.f, 0.f);

        int dmax = d;
        dmax = max(dmax, __shfl_xor(dmax, 16));
        dmax = max(dmax, __shfl_xor(dmax, 32));
        const int nch = __builtin_amdgcn_readfirstlane((dmax + 15) >> 4);

        for (int c = 0; c < nch; ++c) {
            const int jb = c << 4;
            const int ia = min(rs + jb + sl, NE - 1);
            const int ids = csr[ia];          // 64B coalesced per group
            const int rem = d - jb;           // group-uniform
#pragma unroll
            for (int jj = 0; jj < 16; ++jj) {
                const bool v = jj < rem;
                const int sj = v ? jj : 0;    // clamp -> L1-hit duplicate
                const int idx = __shfl(ids, gb + sj);
                const float4 xr = *(const float4*)(x + (size_t)idx * FD + sl * 4);
                const float m = v ? 1.f : 0.f;
                acc.x += m * xr.x;
                acc.y += m * xr.y;
                acc.z += m * xr.z;
                acc.w += m * xr.w;
            }
        }
        const float inv = 1.0f / (float)max(d, 1);
        if (ok) {
            const int f = sl * 4;
            sT[f + 0][nl] = acc.x * inv;
            sT[f + 1][nl] = acc.y * inv;
            sT[f + 2][nl] = acc.z * inv;
            sT[f + 3][nl] = acc.w * inv;
            xT[f + 0][nl] = xv.x;
            xT[f + 1][nl] = xv.y;
            xT[f + 2][nl] = xv.z;
            xT[f + 3][nl] = xv.w;
        }
    }
    __syncthreads();

    // ---- phase B: lane = node, k-slice [kbase, kbase+8) ----
    const int kbase = __builtin_amdgcn_readfirstlane(wid * 8);
    float h[8];
#pragma unroll
    for (int t = 0; t < 8; ++t) h[t] = b1[kbase + t];
#pragma unroll 4
    for (int j = 0; j < FD; ++j) {
        const float sj = sT[j][lane];
        const float xj = xT[j][lane];
        const float* wl = wt1l + j * FD + kbase;
        const float* wr = wt1r + j * FD + kbase;
#pragma unroll
        for (int t = 0; t < 8; ++t) h[t] += sj * wl[t] + xj * wr[t];
    }

    float p0 = 0.f, p1 = 0.f, q0 = 0.f, q1 = 0.f;
#pragma unroll
    for (int t = 0; t < 8; ++t) {
        const float r = fmaxf(h[t], 0.f);
        p0 += r * W2l[kbase + t];
        p1 += r * W2l[FD + kbase + t];
        q0 += r * W2r[kbase + t];
        q1 += r * W2r[FD + kbase + t];
    }
    atomicAdd(&pacc[0 * CHK + lane], p0);
    atomicAdd(&pacc[1 * CHK + lane], p1);
    atomicAdd(&pacc[2 * CHK + lane], q0);
    atomicAdd(&pacc[3 * CHK + lane], q1);
    __syncthreads();

    // ---- write pq: thread t -> (node t>>2, comp t&3), coalesced ----
    {
        const int t = threadIdx.x;
        if (t < 4 * CHK) {
            const int n = base + (t >> 2);
            if (n < NN) {
                const int c = t & 3;
                float v = pacc[c * CHK + (t >> 2)];
                if (c == 2) v += b2[0];
                if (c == 3) v += b2[1];
                pq[(size_t)n * 4 + c] = v;
            }
        }
    }
}

// ---------------------------------------------------------------------------
// K5: layer-2 mean aggregation of p + final add. 16 lanes per node,
//     4 nodes per wave.
__global__ void k_l2(const int* __restrict__ csr, const int* __restrict__ rowstart,
                     const int* __restrict__ deg, const float* __restrict__ pq,
                     float* __restrict__ out) {
    const int gw = (blockIdx.x * blockDim.x + threadIdx.x) >> 6;
    const int lane = threadIdx.x & 63;
    const int sub = lane >> 4;   // node within wave
    const int sl = lane & 15;    // lane within 16-group
    const int n = gw * 4 + sub;
    if (n >= NN) return;
    const int rs = rowstart[n];
    const int d = deg[n];
    float a0 = 0.f, a1 = 0.f;
    for (int i = sl; i < d; i += 16) {
        const int s = csr[rs + i];
        const float2 v = *(const float2*)(pq + 4 * (size_t)s);
        a0 += v.x;
        a1 += v.y;
    }
#pragma unroll
    for (int off = 8; off; off >>= 1) {
        a0 += __shfl_xor(a0, off);
        a1 += __shfl_xor(a1, off);
    }
    if (sl == 0) {
        const float inv = 1.0f / (float)max(d, 1);
        const float2 q = *(const float2*)(pq + 4 * (size_t)n + 2);
        *(float2*)(out + 2 * (size_t)n) = make_float2(a0 * inv + q.x, a1 * inv + q.y);
    }
}

// ---------------------------------------------------------------------------
extern "C" void kernel_launch(void* const* d_in, const int* in_sizes, int n_in,
                              void* d_out, int out_size, void* d_ws, size_t ws_size,
                              hipStream_t stream) {
    const float* x   = (const float*)d_in[0];
    const int*   ei  = (const int*)d_in[1];
    const float* W1l = (const float*)d_in[2];
    const float* b1  = (const float*)d_in[3];
    const float* W1r = (const float*)d_in[4];
    const float* W2l = (const float*)d_in[5];
    const float* b2  = (const float*)d_in[6];
    const float* W2r = (const float*)d_in[7];

    float* out      = (float*)d_out;   // N*2 floats
    float* edge_out = out + 2 * NN;    // 2*E floats (edge_index as float)

    int*   wsi      = (int*)d_ws;
    int*   deg      = wsi + OFF_DEG;
    int*   rowstart = wsi + OFF_ROW;
    int*   partial  = wsi + OFF_PAR;
    int*   rank     = wsi + OFF_RANK;
    int*   csr      = wsi + OFF_CSR;
    float* pq       = (float*)d_ws + OFF_PQ;
    float* wt1l     = (float*)d_ws + OFF_WT;
    float* wt1r     = wt1l + FD * FD;

    hipMemsetAsync(deg, 0, (size_t)NN * sizeof(int), stream);

    k_wt<<<16, 256, 0, stream>>>(W1l, W1r, wt1l, wt1r);
    k_prep<<<2048, 256, 0, stream>>>(ei, deg, rank);
    k_scanA<<<NBLK, 256, 0, stream>>>(deg, partial);
    k_scanB<<<NBLK, 256, 0, stream>>>(deg, partial, rowstart);
    k_build<<<2048, 256, 0, stream>>>(ei, rowstart, rank, csr, edge_out);
    k_l1<<<(NN + CHK - 1) / CHK, 512, 0, stream>>>(csr, rowstart, deg, x,
                                                   wt1l, b1, wt1r,
                                                   W2l, b2, W2r, pq);
    k_l2<<<((NN + 3) / 4 * 64 + 255) / 256, 256, 0, stream>>>(
        csr, rowstart, deg, pq, out);
}

// Round 9
// 156.633 us; speedup vs baseline: 6.8170x; 1.0748x over previous
//
#include <hip/hip_runtime.h>

#define NN 100000   // nodes
#define NE 1000000  // edges
#define FD 64       // feature dim
#define CHK 64      // nodes per block tile in k_l1
#define NBLK 98     // scan blocks: ceil(NN/1024)

// ws layout (4-byte units):
//   deg      : [0, NN)              int
//   rowstart : [NN, 2NN)            int   (exclusive scan of deg)
//   partial  : [2NN, 2NN+128)       int   (scan block sums)
//   rank     : [2NN+128, +NE)       int   (edge rank within its dst row)
//   csr      : [2NN+128+NE, +NE)    int   (src ids grouped by dst)
//   pq       : [2NN+128+2NE, +4NN)  float (p0,p1,q0,q1 per node)
//   wt       : next, 2*4096 floats  (W1l^T, W1r^T: [j][k] layouts)
// total ~ 10.5 MB

#define OFF_DEG 0
#define OFF_ROW (NN)
#define OFF_PAR (2 * NN)
#define OFF_RANK (2 * NN + 128)
#define OFF_CSR (2 * NN + 128 + NE)
#define OFF_PQ  (2 * NN + 128 + 2 * NE)
#define OFF_WT  (2 * NN + 128 + 2 * NE + 4 * NN)

// ---------------------------------------------------------------------------
// K0 (fused init): edge_index -> float output tail (int4/float4), deg zeroing,
// and layer-1 weight transpose. One launch instead of three.
__global__ void k_init(const int* __restrict__ ei, float* __restrict__ edge_out,
                       int* __restrict__ deg,
                       const float* __restrict__ W1l, const float* __restrict__ W1r,
                       float* __restrict__ wt1l, float* __restrict__ wt1r) {
    const int tid = blockIdx.x * blockDim.x + threadIdx.x;
    if (tid < 2 * NE / 4) {
        const int4 v = *((const int4*)ei + tid);
        float4 f;
        f.x = (float)v.x; f.y = (float)v.y; f.z = (float)v.z; f.w = (float)v.w;
        *((float4*)edge_out + tid) = f;
    }
    if (tid < NN / 4) *((int4*)deg + tid) = make_int4(0, 0, 0, 0);
    if (tid < FD * FD) {
        const int k = tid >> 6, j = tid & 63;
        wt1l[j * FD + k] = W1l[tid];
        wt1r[j * FD + k] = W1r[tid];
    }
}

// ---------------------------------------------------------------------------
// K1: in-degree counts + per-edge rank within its dst row (int4, 4 edges/thr).
__global__ void k_prep(const int* __restrict__ ei, int* __restrict__ deg,
                       int* __restrict__ rank) {
    const int i = blockIdx.x * blockDim.x + threadIdx.x;
    if (i >= NE / 4) return;
    const int4 d = *((const int4*)(ei + NE) + i);
    int4 r;
    r.x = atomicAdd(&deg[d.x], 1);
    r.y = atomicAdd(&deg[d.y], 1);
    r.z = atomicAdd(&deg[d.z], 1);
    r.w = atomicAdd(&deg[d.w], 1);
    *((int4*)rank + i) = r;
}

// ---------------------------------------------------------------------------
// K2a: per-block (1024-elem) sums of deg -> partial[b]
__global__ __launch_bounds__(256) void k_scanA(const int* __restrict__ deg,
                                               int* __restrict__ partial) {
    __shared__ int lds[256];
    int t = threadIdx.x;
    int base = blockIdx.x * 1024 + t * 4;
    int s_t = 0;
    if (base < NN) {  // NN % 4 == 0
        int4 v = *(const int4*)(deg + base);
        s_t = v.x + v.y + v.z + v.w;
    }
    lds[t] = s_t;
    __syncthreads();
    for (int s = 128; s; s >>= 1) {
        if (t < s) lds[t] += lds[t + s];
        __syncthreads();
    }
    if (t == 0) partial[blockIdx.x] = lds[0];
}

// K2b: block offset + intra-block exclusive scan -> rowstart[i]
__global__ __launch_bounds__(256) void k_scanB(const int* __restrict__ deg,
                                               const int* __restrict__ partial,
                                               int* __restrict__ rowstart) {
    __shared__ int lds[256];
    int t = threadIdx.x, b = blockIdx.x;
    lds[t] = (t < b && t < NBLK) ? partial[t] : 0;
    __syncthreads();
    for (int s = 128; s; s >>= 1) {
        if (t < s) lds[t] += lds[t + s];
        __syncthreads();
    }
    int bo = lds[0];
    __syncthreads();

    int base = b * 1024 + t * 4;
    int4 v = make_int4(0, 0, 0, 0);
    if (base < NN) v = *(const int4*)(deg + base);
    int s_t = v.x + v.y + v.z + v.w;

    lds[t] = s_t;
    __syncthreads();
    for (int off = 1; off < 256; off <<= 1) {
        int v2 = lds[t];
        if (t >= off) v2 += lds[t - off];
        __syncthreads();
        lds[t] = v2;
        __syncthreads();
    }
    int excl = lds[t] - s_t;
    if (base < NN) {
        int r = bo + excl;
        int4 out;
        out.x = r;
        out.y = r + v.x;
        out.z = r + v.x + v.y;
        out.w = r + v.x + v.y + v.z;
        *(int4*)(rowstart + base) = out;
    }
}

// ---------------------------------------------------------------------------
// K3: pure scatter (no atomics), int4 streaming reads, 4 edges/thread.
__global__ void k_build(const int* __restrict__ ei, const int* __restrict__ rowstart,
                        const int* __restrict__ rank, int* __restrict__ csr) {
    const int i = blockIdx.x * blockDim.x + threadIdx.x;
    if (i >= NE / 4) return;
    const int4 s = *((const int4*)ei + i);
    const int4 d = *((const int4*)(ei + NE) + i);
    const int4 r = *((const int4*)rank + i);
    csr[rowstart[d.x] + r.x] = s.x;
    csr[rowstart[d.y] + r.y] = s.y;
    csr[rowstart[d.z] + r.z] = s.z;
    csr[rowstart[d.w] + r.w] = s.w;
}

// ---------------------------------------------------------------------------
// K4: fused layer-1, one 64-node tile per block (8 waves, 512 threads).
//  phase A: wave splits into 4 groups of 16 lanes; each group owns one node
//    and fetches whole 256B neighbor rows as float4. Loads are STAGED in
//    explicit 8-deep register batches fenced by sched_barrier(0) so 8 row
//    loads stay in flight per wave (R8: compiler collapsed to ~3 @ 44 VGPR).
//    Second 8-batch of a chunk is skipped when wave-max remaining degree <= 8.
//  phase B: lane = node, wave w covers k-slice [8w, 8w+8). h[8] in registers;
//    per j: 2 ds_read_b32 + wave-uniform (scalar) loads of transposed weights;
//    relu + W2 fold per-lane; cross-wave combine via LDS atomics.
__global__ __launch_bounds__(512, 4) void k_l1(
    const int* __restrict__ csr, const int* __restrict__ rowstart,
    const int* __restrict__ deg, const float* __restrict__ x,
    const float* __restrict__ wt1l, const float* __restrict__ b1,
    const float* __restrict__ wt1r,
    const float* __restrict__ W2l, const float* __restrict__ b2,
    const float* __restrict__ W2r,
    float* __restrict__ pq) {
    __shared__ float sT[FD][CHK + 1];   // aggr, transposed   16.6 KB
    __shared__ float xT[FD][CHK + 1];   // self x, transposed 16.6 KB
    __shared__ float pacc[4 * CHK];     // 1 KB
    const int lane = threadIdx.x & 63;
    const int wid = threadIdx.x >> 6;   // 0..7
    const int g = lane >> 4;            // group 0..3
    const int sl = lane & 15;           // lane within group
    const int gb = g << 4;              // group base lane
    const int base = blockIdx.x * CHK;

    if (threadIdx.x < 4 * CHK) pacc[threadIdx.x] = 0.f;

    // ---- phase A: 2 rounds x 4 nodes per wave ----
    for (int r = 0; r < 2; ++r) {
        const int nl = wid * 8 + r * 4 + g;  // 0..63
        const int n = base + nl;
        const bool ok = n < NN;
        const int nn = ok ? n : NN - 1;
        const int d = deg[nn];               // group-uniform
        const int rs = rowstart[nn];
        const float4 xv = *(const float4*)(x + (size_t)nn * FD + sl * 4);
        float4 acc = make_float4(0.f, 0.f, 0.f, 0.f);

        int dmax = d;
        dmax = max(dmax, __shfl_xor(dmax, 16));
        dmax = max(dmax, __shfl_xor(dmax, 32));
        const int dmaxu = __builtin_amdgcn_readfirstlane(dmax);  // wave max
        const int nch = (dmaxu + 15) >> 4;

        for (int c = 0; c < nch; ++c) {
            const int jb = c << 4;
            const int ia = min(rs + jb + sl, NE - 1);
            const int ids = csr[ia];          // 64B coalesced per group
            const int rem = d - jb;           // group-uniform (may be <=0)
            const int rc = max(rem - 1, 0);   // clamp index
#pragma unroll
            for (int half = 0; half < 2; ++half) {
                if (half == 1 && (dmaxu - jb) <= 8) break;  // wave-uniform skip
                float4 buf[8];
#pragma unroll
                for (int t = 0; t < 8; ++t) {
                    const int jt = half * 8 + t;
                    const int sj = min(jt, rc);
                    const int idx = __shfl(ids, gb + sj);
                    buf[t] = *(const float4*)(x + (size_t)idx * FD + sl * 4);
                }
                __builtin_amdgcn_sched_barrier(0);  // keep 8 loads in flight
#pragma unroll
                for (int t = 0; t < 8; ++t) {
                    const int jt = half * 8 + t;
                    const float m = (jt < rem) ? 1.f : 0.f;
                    acc.x += m * buf[t].x;
                    acc.y += m * buf[t].y;
                    acc.z += m * buf[t].z;
                    acc.w += m * buf[t].w;
                }
            }
        }
        const float inv = 1.0f / (float)max(d, 1);
        if (ok) {
            const int f = sl * 4;
            sT[f + 0][nl] = acc.x * inv;
            sT[f + 1][nl] = acc.y * inv;
            sT[f + 2][nl] = acc.z * inv;
            sT[f + 3][nl] = acc.w * inv;
            xT[f + 0][nl] = xv.x;
            xT[f + 1][nl] = xv.y;
            xT[f + 2][nl] = xv.z;
            xT[f + 3][nl] = xv.w;
        }
    }
    __syncthreads();

    // ---- phase B: lane = node, k-slice [kbase, kbase+8) ----
    const int kbase = __builtin_amdgcn_readfirstlane(wid * 8);
    float h[8];
#pragma unroll
    for (int t = 0; t < 8; ++t) h[t] = b1[kbase + t];
#pragma unroll 4
    for (int j = 0; j < FD; ++j) {
        const float sj = sT[j][lane];
        const float xj = xT[j][lane];
        const float* wl = wt1l + j * FD + kbase;
        const float* wr = wt1r + j * FD + kbase;
#pragma unroll
        for (int t = 0; t < 8; ++t) h[t] += sj * wl[t] + xj * wr[t];
    }

    float p0 = 0.f, p1 = 0.f, q0 = 0.f, q1 = 0.f;
#pragma unroll
    for (int t = 0; t < 8; ++t) {
        const float r = fmaxf(h[t], 0.f);
        p0 += r * W2l[kbase + t];
        p1 += r * W2l[FD + kbase + t];
        q0 += r * W2r[kbase + t];
        q1 += r * W2r[FD + kbase + t];
    }
    atomicAdd(&pacc[0 * CHK + lane], p0);
    atomicAdd(&pacc[1 * CHK + lane], p1);
    atomicAdd(&pacc[2 * CHK + lane], q0);
    atomicAdd(&pacc[3 * CHK + lane], q1);
    __syncthreads();

    // ---- write pq: thread t -> (node t>>2, comp t&3), coalesced ----
    {
        const int t = threadIdx.x;
        if (t < 4 * CHK) {
            const int n = base + (t >> 2);
            if (n < NN) {
                const int c = t & 3;
                float v = pacc[c * CHK + (t >> 2)];
                if (c == 2) v += b2[0];
                if (c == 3) v += b2[1];
                pq[(size_t)n * 4 + c] = v;
            }
        }
    }
}

// ---------------------------------------------------------------------------
// K5: layer-2 mean aggregation of p + final add. 16 lanes per node,
//     4 nodes per wave.
__global__ void k_l2(const int* __restrict__ csr, const int* __restrict__ rowstart,
                     const int* __restrict__ deg, const float* __restrict__ pq,
                     float* __restrict__ out) {
    const int gw = (blockIdx.x * blockDim.x + threadIdx.x) >> 6;
    const int lane = threadIdx.x & 63;
    const int sub = lane >> 4;   // node within wave
    const int sl = lane & 15;    // lane within 16-group
    const int n = gw * 4 + sub;
    if (n >= NN) return;
    const int rs = rowstart[n];
    const int d = deg[n];
    float a0 = 0.f, a1 = 0.f;
    for (int i = sl; i < d; i += 16) {
        const int s = csr[rs + i];
        const float2 v = *(const float2*)(pq + 4 * (size_t)s);
        a0 += v.x;
        a1 += v.y;
    }
#pragma unroll
    for (int off = 8; off; off >>= 1) {
        a0 += __shfl_xor(a0, off);
        a1 += __shfl_xor(a1, off);
    }
    if (sl == 0) {
        const float inv = 1.0f / (float)max(d, 1);
        const float2 q = *(const float2*)(pq + 4 * (size_t)n + 2);
        *(float2*)(out + 2 * (size_t)n) = make_float2(a0 * inv + q.x, a1 * inv + q.y);
    }
}

// ---------------------------------------------------------------------------
extern "C" void kernel_launch(void* const* d_in, const int* in_sizes, int n_in,
                              void* d_out, int out_size, void* d_ws, size_t ws_size,
                              hipStream_t stream) {
    const float* x   = (const float*)d_in[0];
    const int*   ei  = (const int*)d_in[1];
    const float* W1l = (const float*)d_in[2];
    const float* b1  = (const float*)d_in[3];
    const float* W1r = (const float*)d_in[4];
    const float* W2l = (const float*)d_in[5];
    const float* b2  = (const float*)d_in[6];
    const float* W2r = (const float*)d_in[7];

    float* out      = (float*)d_out;   // N*2 floats
    float* edge_out = out + 2 * NN;    // 2*E floats (edge_index as float)

    int*   wsi      = (int*)d_ws;
    int*   deg      = wsi + OFF_DEG;
    int*   rowstart = wsi + OFF_ROW;
    int*   partial  = wsi + OFF_PAR;
    int*   rank     = wsi + OFF_RANK;
    int*   csr      = wsi + OFF_CSR;
    float* pq       = (float*)d_ws + OFF_PQ;
    float* wt1l     = (float*)d_ws + OFF_WT;
    float* wt1r     = wt1l + FD * FD;

    k_init<<<2048, 256, 0, stream>>>(ei, edge_out, deg, W1l, W1r, wt1l, wt1r);
    k_prep<<<(NE / 4 + 255) / 256, 256, 0, stream>>>(ei, deg, rank);
    k_scanA<<<NBLK, 256, 0, stream>>>(deg, partial);
    k_scanB<<<NBLK, 256, 0, stream>>>(deg, partial, rowstart);
    k_build<<<(NE / 4 + 255) / 256, 256, 0, stream>>>(ei, rowstart, rank, csr);
    k_l1<<<(NN + CHK - 1) / CHK, 512, 0, stream>>>(csr, rowstart, deg, x,
                                                   wt1l, b1, wt1r,
                                                   W2l, b2, W2r, pq);
    k_l2<<<((NN + 3) / 4 * 64 + 255) / 256, 256, 0, stream>>>(
        csr, rowstart, deg, pq, out);
}